// Round 7
// baseline (2263.581 us; speedup 1.0000x reference)
//
#include <hip/hip_runtime.h>
#include <hip/hip_bf16.h>
#include <hip/hip_fp16.h>
#include <cstddef>
#include <cstdint>

// Problem constants (from reference)
#define Nn 50000
#define Ee 800000
#define Tt 8
#define Ff 128
#define Hh 128
#define Cc 10
#define Gg 64
#define NT 400000    // Tt * Nn

typedef __attribute__((ext_vector_type(8))) short bf16x8;
typedef __attribute__((ext_vector_type(4))) float f32x4;

__device__ inline unsigned short f2bf(float x) {
    __hip_bfloat16 b = __float2bfloat16(x);
    return *reinterpret_cast<unsigned short*>(&b);
}
__device__ inline float bf2f(unsigned short u) {
    __hip_bfloat16 b = *reinterpret_cast<__hip_bfloat16*>(&u);
    return __bfloat162float(b);
}
__device__ inline void split2(float x, unsigned short& h, unsigned short& l) {
    h = f2bf(x);
    l = f2bf(x - bf2f(h));
}

// ---------------------------------------------------------------------------
// Degree / normalization / CSR build
// ---------------------------------------------------------------------------
__global__ __launch_bounds__(256) void count_deg_kernel(const int* __restrict__ dst,
                                                        int* __restrict__ counts) {
    int e = blockIdx.x * 256 + threadIdx.x;
    if (e < Ee) atomicAdd(&counts[dst[e]], 1);
}

__global__ __launch_bounds__(256) void dis_kernel(const int* __restrict__ counts,
                                                  float* __restrict__ dis) {
    int i = blockIdx.x * 256 + threadIdx.x;
    if (i < Nn) dis[i] = 1.0f / sqrtf((float)counts[i] + 1.0f);
}

__global__ __launch_bounds__(256) void scan_block_kernel(const int* __restrict__ counts,
                                                         int* __restrict__ incl,
                                                         int* __restrict__ blksum) {
    __shared__ int s[256];
    int t = threadIdx.x;
    int i = blockIdx.x * 256 + t;
    int v = (i < Nn) ? counts[i] : 0;
    s[t] = v;
    __syncthreads();
    #pragma unroll
    for (int d = 1; d < 256; d <<= 1) {
        int add = (t >= d) ? s[t - d] : 0;
        __syncthreads();
        s[t] += add;
        __syncthreads();
    }
    if (i < Nn) incl[i] = s[t];
    if (t == 255) blksum[blockIdx.x] = s[255];
}

__global__ __launch_bounds__(256) void scan_tops_kernel(int* __restrict__ blksum, int nb) {
    __shared__ int s[256];
    int t = threadIdx.x;
    int v = (t < nb) ? blksum[t] : 0;
    s[t] = v;
    __syncthreads();
    #pragma unroll
    for (int d = 1; d < 256; d <<= 1) {
        int add = (t >= d) ? s[t - d] : 0;
        __syncthreads();
        s[t] += add;
        __syncthreads();
    }
    if (t < nb) blksum[t] = s[t] - v;  // exclusive
}

__global__ __launch_bounds__(256) void scan_fix_kernel(const int* __restrict__ counts,
                                                       const int* __restrict__ incl,
                                                       const int* __restrict__ blksum,
                                                       int* __restrict__ off) {
    int i = blockIdx.x * 256 + threadIdx.x;
    if (i < Nn) off[i] = incl[i] - counts[i] + blksum[i >> 8];
}

__global__ __launch_bounds__(256) void fill_csr_kernel(const int* __restrict__ src,
                                                       const int* __restrict__ dst,
                                                       const float* __restrict__ dis,
                                                       const int* __restrict__ off,
                                                       int* __restrict__ cursor,
                                                       int* __restrict__ csr_src,
                                                       float* __restrict__ csr_w) {
    int e = blockIdx.x * 256 + threadIdx.x;
    if (e >= Ee) return;
    int s = src[e], d = dst[e];
    int slot = off[d] + atomicAdd(&cursor[d], 1);
    csr_src[slot] = s;
    csr_w[slot] = dis[s] * dis[d];
}

// ---------------------------------------------------------------------------
// Weight split kernels (fp32 -> bf16 hi/lo, layout B^T [col][K])
// ---------------------------------------------------------------------------
__global__ __launch_bounds__(256) void wsplit_kernel(const float* __restrict__ W,
                                                     unsigned short* __restrict__ bh,
                                                     unsigned short* __restrict__ bl, int n) {
    int i = blockIdx.x * 256 + threadIdx.x;
    if (i >= n) return;
    unsigned short h, l;
    split2(W[i], h, l);
    bh[i] = h;
    bl[i] = l;
}

__global__ __launch_bounds__(256) void wgcnT_kernel(const float* __restrict__ W,
                                                    unsigned short* __restrict__ bh,
                                                    unsigned short* __restrict__ bl) {
    int i = blockIdx.x * 256 + threadIdx.x;
    if (i >= 128 * 128) return;
    int f = i >> 7, hc = i & 127;
    unsigned short h, l;
    split2(W[i], h, l);
    bh[hc * 128 + f] = h;
    bl[hc * 128 + f] = l;
}

// ---------------------------------------------------------------------------
// xw GEMM: xwp[(n*8+t)][128] = x_seq[(t*Nn+n)][128] @ W_gcn, split-bf16 MFMA.
// ---------------------------------------------------------------------------
__global__ __launch_bounds__(256) void xw_gemm(const float* __restrict__ X,
                                               const unsigned short* __restrict__ BTh,
                                               const unsigned short* __restrict__ BTl,
                                               float* __restrict__ Cout) {
    __shared__ __align__(16) char lds[32768];
    char* pAh = lds;
    char* pAl = lds + 16384;
    const int bm = blockIdx.x * 128;
    const int tid = threadIdx.x;
    const int wid = tid >> 6, lane = tid & 63;
    const int wr = wid >> 1, wc = wid & 1;
    const int l15 = lane & 15, l4 = lane >> 4;

    f32x4 acc[4][4] = {};

    for (int kh = 0; kh < 2; ++kh) {
        if (kh) __syncthreads();
        #pragma unroll
        for (int i = 0; i < 8; ++i) {
            int idx = tid + i * 256;
            int row = idx >> 4;
            int k4 = idx & 15;
            float4 v = *(const float4*)(X + (size_t)(bm + row) * 128 + kh * 64 + k4 * 4);
            ushort4 h, l;
            split2(v.x, h.x, l.x);
            split2(v.y, h.y, l.y);
            split2(v.z, h.z, l.z);
            split2(v.w, h.w, l.w);
            int off = row * 128 + ((k4 * 8) ^ ((row & 7) << 4));
            *(ushort4*)(pAh + off) = h;
            *(ushort4*)(pAl + off) = l;
        }
        __syncthreads();

        #pragma unroll
        for (int kq = 0; kq < 2; ++kq) {
            bf16x8 a_h[4], a_l[4], b_h[4], b_l[4];
            const int kbase = kq * 64 + l4 * 16;
            #pragma unroll
            for (int m = 0; m < 4; ++m) {
                const int r = wr * 64 + m * 16 + l15;
                const int byteo = r * 128 + (kbase ^ ((r & 7) << 4));
                a_h[m] = *(const bf16x8*)(pAh + byteo);
                a_l[m] = *(const bf16x8*)(pAl + byteo);
            }
            #pragma unroll
            for (int n = 0; n < 4; ++n) {
                const int col = wc * 64 + n * 16 + l15;
                const size_t bo = (size_t)col * 128 + kh * 64 + kq * 32 + l4 * 8;
                b_h[n] = *(const bf16x8*)(BTh + bo);
                b_l[n] = *(const bf16x8*)(BTl + bo);
            }
            #pragma unroll
            for (int m = 0; m < 4; ++m)
                #pragma unroll
                for (int n = 0; n < 4; ++n) {
                    acc[m][n] = __builtin_amdgcn_mfma_f32_16x16x32_bf16(a_h[m], b_h[n],
                                                                        acc[m][n], 0, 0, 0);
                    acc[m][n] = __builtin_amdgcn_mfma_f32_16x16x32_bf16(a_h[m], b_l[n],
                                                                        acc[m][n], 0, 0, 0);
                    acc[m][n] = __builtin_amdgcn_mfma_f32_16x16x32_bf16(a_l[m], b_h[n],
                                                                        acc[m][n], 0, 0, 0);
                }
        }
    }

    // epilogue: remap GEMM row r = t*Nn + n  ->  output row n*8 + t
    #pragma unroll
    for (int m = 0; m < 4; ++m) {
        const int row = bm + wr * 64 + m * 16 + l4 * 4;
        #pragma unroll
        for (int q = 0; q < 4; ++q) {
            const int r = row + q;
            const int tt = r / Nn;
            const int nn = r - tt * Nn;
            float* outrow = Cout + ((size_t)nn * 8 + tt) * 128;
            #pragma unroll
            for (int n = 0; n < 4; ++n) {
                const int col = wc * 64 + n * 16 + l15;
                outrow[col] = acc[m][n][q];
            }
        }
    }
}

// ---------------------------------------------------------------------------
// FUSED aggregation + gx GEMM. One block = 8 nodes = 64 rows.
// Phase A: gather xwp 4KB node-blocks (gcn stays in LDS, bf16 hi/lo swizzled).
// Phase B: gx = gcn @ W_ih^T + b_ih -> fp16, NEW layout [t][n][384]
//          (row = t*Nn + node), so the GRU reads contiguous per-t tiles.
// ---------------------------------------------------------------------------
__global__ __launch_bounds__(256) void aggx_kernel(const float* __restrict__ xwp,
                                                   const float* __restrict__ dis,
                                                   const int* __restrict__ off,
                                                   const int* __restrict__ counts,
                                                   const int* __restrict__ csr_src,
                                                   const float* __restrict__ csr_w,
                                                   const float* __restrict__ b_gcn,
                                                   const unsigned short* __restrict__ BTh,
                                                   const unsigned short* __restrict__ BTl,
                                                   const float* __restrict__ bias,
                                                   __half* __restrict__ gx16) {
    __shared__ __align__(16) char lds[32768];  // gcn hi 16KB + lo 16KB
    char* pAh = lds;
    char* pAl = lds + 16384;
    const int n0 = blockIdx.x * 8;
    const int tid = threadIdx.x;
    const int wid = tid >> 6, lane = tid & 63;
    const int l15 = lane & 15, l4 = lane >> 4;

    // ---- Phase A: aggregate 2 nodes per wave ----
    for (int nl = 0; nl < 2; ++nl) {
        const int n = n0 + wid * 2 + nl;
        const float dv = dis[n];
        const float dsq = dv * dv;
        const float* bn_ = xwp + (size_t)n * 1024 + lane * 4;
        f32x4 acc[4];
        #pragma unroll
        for (int p = 0; p < 4; ++p) acc[p] = (*(const f32x4*)(bn_ + p * 256)) * dsq;

        const int s0 = off[n];
        const int cnt = counts[n];
        for (int base = 0; base < cnt; base += 64) {
            const int m = min(64, cnt - base);
            int idxv = 0;
            float wvv = 0.f;
            {
                int j = base + lane;
                if (j < cnt) {
                    idxv = csr_src[s0 + j];
                    wvv = csr_w[s0 + j];
                }
            }
            int sA = __shfl(idxv, 0);
            float wA = __shfl(wvv, 0);
            const float* pA = xwp + (size_t)sA * 1024 + lane * 4;
            f32x4 v0 = *(const f32x4*)(pA);
            f32x4 v1 = *(const f32x4*)(pA + 256);
            f32x4 v2 = *(const f32x4*)(pA + 512);
            f32x4 v3 = *(const f32x4*)(pA + 768);
            for (int k = 0; k < m; ++k) {
                f32x4 u0 = v0, u1 = v1, u2 = v2, u3 = v3;
                const float w = wA;
                if (k + 1 < m) {
                    sA = __shfl(idxv, k + 1);
                    wA = __shfl(wvv, k + 1);
                    const float* pN = xwp + (size_t)sA * 1024 + lane * 4;
                    v0 = *(const f32x4*)(pN);
                    v1 = *(const f32x4*)(pN + 256);
                    v2 = *(const f32x4*)(pN + 512);
                    v3 = *(const f32x4*)(pN + 768);
                }
                acc[0] += u0 * w;
                acc[1] += u1 * w;
                acc[2] += u2 * w;
                acc[3] += u3 * w;
            }
        }

        #pragma unroll
        for (int p = 0; p < 4; ++p) {
            const int q = p * 1024 + lane * 16;  // byte in node's 4KB block
            const int t = q >> 9;
            const int c0 = (q & 511) >> 2;
            float4 bb = *(const float4*)(b_gcn + c0);
            float w0 = fmaxf(acc[p][0] + bb.x, 0.f);
            float w1 = fmaxf(acc[p][1] + bb.y, 0.f);
            float w2 = fmaxf(acc[p][2] + bb.z, 0.f);
            float w3 = fmaxf(acc[p][3] + bb.w, 0.f);
            ushort4 oh, ol;
            split2(w0, oh.x, ol.x);
            split2(w1, oh.y, ol.y);
            split2(w2, oh.z, ol.z);
            split2(w3, oh.w, ol.w);
            const int r = (wid * 2 + nl) * 8 + t;        // local row, r&7 == t
            const int byteo = r * 256 + ((c0 * 2) ^ (t << 4));
            *(ushort4*)(pAh + byteo) = oh;
            *(ushort4*)(pAl + byteo) = ol;
        }
    }
    __syncthreads();

    // ---- Phase B: gx = gcn @ W_ih^T + b_ih, wave owns 96 cols ----
    f32x4 acc[4][6] = {};
    const int wc0 = wid * 96;
    #pragma unroll
    for (int kq = 0; kq < 4; ++kq) {
        bf16x8 a_h[4], a_l[4];
        const int kbase = kq * 64 + l4 * 16;
        #pragma unroll
        for (int m = 0; m < 4; ++m) {
            const int r = m * 16 + l15;
            const int byteo = r * 256 + (kbase ^ ((r & 7) << 4));
            a_h[m] = *(const bf16x8*)(pAh + byteo);
            a_l[m] = *(const bf16x8*)(pAl + byteo);
        }
        #pragma unroll
        for (int n = 0; n < 6; ++n) {
            const int col = wc0 + n * 16 + l15;
            const size_t bo = (size_t)col * 128 + kq * 32 + l4 * 8;
            bf16x8 b_h = *(const bf16x8*)(BTh + bo);
            bf16x8 b_l = *(const bf16x8*)(BTl + bo);
            #pragma unroll
            for (int m = 0; m < 4; ++m) {
                acc[m][n] = __builtin_amdgcn_mfma_f32_16x16x32_bf16(a_h[m], b_h,
                                                                    acc[m][n], 0, 0, 0);
                acc[m][n] = __builtin_amdgcn_mfma_f32_16x16x32_bf16(a_h[m], b_l,
                                                                    acc[m][n], 0, 0, 0);
                acc[m][n] = __builtin_amdgcn_mfma_f32_16x16x32_bf16(a_l[m], b_h,
                                                                    acc[m][n], 0, 0, 0);
            }
        }
    }

    // epilogue: local row lr = node_local*8 + t  ->  gx row t*Nn + node
    #pragma unroll
    for (int n = 0; n < 6; ++n) {
        const int col = wc0 + n * 16 + l15;
        const float bb = bias[col];
        #pragma unroll
        for (int m = 0; m < 4; ++m) {
            #pragma unroll
            for (int q = 0; q < 4; ++q) {
                const int lr = m * 16 + l4 * 4 + q;
                const int tt = lr & 7;
                const int node = n0 + (lr >> 3);
                gx16[((size_t)tt * Nn + node) * 384 + col] = __float2half(acc[m][n][q] + bb);
            }
        }
    }
}

// ---------------------------------------------------------------------------
// GRU v2: ONE WAVE per 16 nodes, zero barriers. Wave owns 16 rows x 384 cols
// of gh; with MFMA C-layout (col=l15+16nt, row=l4*4+q) the gate is fully
// register-local (lane holds gh at c, c+128, c+256 AND the h it updates).
// gx[t][n][384] tile (12KB contiguous) prefetched via global_load_lds before
// the MFMA phase; wave-local vmcnt(0) before the gate. h round-trips through
// a 272B-stride LDS buffer to become next step's A-fragments.
// ---------------------------------------------------------------------------
__global__ __launch_bounds__(64, 2) void gru_kernel(const unsigned short* __restrict__ BTh,
                                                    const unsigned short* __restrict__ BTl,
                                                    const __half* __restrict__ gx,
                                                    const float* __restrict__ b_hh,
                                                    float* __restrict__ hbuf) {
    __shared__ __align__(16) char lds[20992];  // hHi 4352 | hLo 4352 | gxS 12288
    char* pHh = lds;
    char* pHl = lds + 4352;
    char* gxS = lds + 8704;
    const int lane = threadIdx.x;
    const int l15 = lane & 15, l4 = lane >> 4;
    const int n0 = blockIdx.x * 16;

    // biases for this lane's 24 cols (l15 + 16n | +128 | +256)
    float bhr[8], bhz[8], bhn[8];
    #pragma unroll
    for (int n = 0; n < 8; ++n) {
        bhr[n] = b_hh[l15 + 16 * n];
        bhz[n] = b_hh[l15 + 16 * n + 128];
        bhn[n] = b_hh[l15 + 16 * n + 256];
    }

    // issue gx tile load for step t (12KB contiguous; rows n0..n0+15)
    #define ISSUE_GX(T)                                                                  \
        {                                                                                \
            const char* srcb = (const char*)(gx + ((size_t)(T) * Nn + n0) * 384);        \
            _Pragma("unroll")                                                            \
            for (int i = 0; i < 12; ++i) {                                               \
                const int o = i * 1024 + lane * 16;                                      \
                __builtin_amdgcn_global_load_lds(                                        \
                    (const __attribute__((address_space(1))) void*)(srcb + o),           \
                    (__attribute__((address_space(3))) void*)(gxS + o), 16, 0, 0);       \
            }                                                                            \
        }

    ISSUE_GX(0);

    float h[32];  // h[n*4+q] = h[row=l4*4+q][col=l15+16n]

    // ---- t = 0: gh = 0 (h=0) -> pre-activations = gx + b_hh ----
    asm volatile("s_waitcnt vmcnt(0)" ::: "memory");
    __builtin_amdgcn_sched_barrier(0);
    #pragma unroll
    for (int n = 0; n < 8; ++n) {
        const int cb = (l15 + 16 * n) * 2;
        #pragma unroll
        for (int q = 0; q < 4; ++q) {
            const char* rp = gxS + (l4 * 4 + q) * 768;
            float xr = __half2float(*(const __half*)(rp + cb));
            float xz = __half2float(*(const __half*)(rp + cb + 256));
            float xn = __half2float(*(const __half*)(rp + cb + 512));
            float rg = 1.f / (1.f + expf(-(xr + bhr[n])));
            float zg = 1.f / (1.f + expf(-(xz + bhz[n])));
            float ng = tanhf(xn + rg * bhn[n]);
            h[n * 4 + q] = (1.f - zg) * ng;
        }
    }

    for (int t = 1; t < Tt; ++t) {
        // ---- write h -> hLDS (bf16 hi/lo, row stride 272B) ----
        #pragma unroll
        for (int n = 0; n < 8; ++n) {
            #pragma unroll
            for (int q = 0; q < 4; ++q) {
                const int byteo = (l4 * 4 + q) * 272 + (l15 + 16 * n) * 2;
                unsigned short sh, sl;
                split2(h[n * 4 + q], sh, sl);
                *(unsigned short*)(pHh + byteo) = sh;
                *(unsigned short*)(pHl + byteo) = sl;
            }
        }
        // gxS reads of step t-1 all retired before DMA overwrites gxS
        asm volatile("s_waitcnt lgkmcnt(0)" ::: "memory");
        __builtin_amdgcn_sched_barrier(0);
        ISSUE_GX(t);

        // ---- MFMA: gh = h @ W_hh^T, 16 rows x 384 cols, acc in regs ----
        f32x4 acc[24];
        #pragma unroll
        for (int i = 0; i < 24; ++i) acc[i] = (f32x4){0.f, 0.f, 0.f, 0.f};
        #pragma unroll
        for (int kq = 0; kq < 4; ++kq) {
            const int ab = l15 * 272 + kq * 64 + l4 * 16;
            bf16x8 a_h = *(const bf16x8*)(pHh + ab);
            bf16x8 a_l = *(const bf16x8*)(pHl + ab);
            #pragma unroll
            for (int nt = 0; nt < 24; ++nt) {
                const int col = nt * 16 + l15;
                const size_t bo = (size_t)col * 128 + kq * 32 + l4 * 8;
                bf16x8 b_h = *(const bf16x8*)(BTh + bo);
                bf16x8 b_l = *(const bf16x8*)(BTl + bo);
                acc[nt] = __builtin_amdgcn_mfma_f32_16x16x32_bf16(a_h, b_h, acc[nt], 0, 0, 0);
                acc[nt] = __builtin_amdgcn_mfma_f32_16x16x32_bf16(a_h, b_l, acc[nt], 0, 0, 0);
                acc[nt] = __builtin_amdgcn_mfma_f32_16x16x32_bf16(a_l, b_h, acc[nt], 0, 0, 0);
            }
        }

        // ---- gate (register-local; gx tile has landed) ----
        asm volatile("s_waitcnt vmcnt(0)" ::: "memory");
        __builtin_amdgcn_sched_barrier(0);
        #pragma unroll
        for (int n = 0; n < 8; ++n) {
            const int cb = (l15 + 16 * n) * 2;
            #pragma unroll
            for (int q = 0; q < 4; ++q) {
                const char* rp = gxS + (l4 * 4 + q) * 768;
                float xr = __half2float(*(const __half*)(rp + cb));
                float xz = __half2float(*(const __half*)(rp + cb + 256));
                float xn = __half2float(*(const __half*)(rp + cb + 512));
                float ghr = acc[n][q] + bhr[n];
                float ghz = acc[n + 8][q] + bhz[n];
                float ghn = acc[n + 16][q] + bhn[n];
                float rg = 1.f / (1.f + expf(-(xr + ghr)));
                float zg = 1.f / (1.f + expf(-(xz + ghz)));
                float ng = tanhf(xn + rg * ghn);
                h[n * 4 + q] = (1.f - zg) * ng + zg * h[n * 4 + q];
            }
        }
    }

    // ---- write final h ----
    #pragma unroll
    for (int n = 0; n < 8; ++n)
        #pragma unroll
        for (int q = 0; q < 4; ++q)
            hbuf[(size_t)(n0 + l4 * 4 + q) * 128 + l15 + 16 * n] = h[n * 4 + q];
    #undef ISSUE_GX
}

// ---------------------------------------------------------------------------
// Graph sizes by binary search on the SORTED batch array
// ---------------------------------------------------------------------------
__global__ void gcount_bs_kernel(const int* __restrict__ batch, float* __restrict__ ginv) {
    int g = threadIdx.x;
    if (g >= Gg) return;
    int lo = 0, hi = Nn;
    while (lo < hi) {
        int m = (lo + hi) >> 1;
        if (batch[m] < g) lo = m + 1; else hi = m;
    }
    int start = lo;
    lo = 0; hi = Nn;
    while (lo < hi) {
        int m = (lo + hi) >> 1;
        if (batch[m] <= g) lo = m + 1; else hi = m;
    }
    ginv[g] = 1.f / fmaxf((float)(lo - start), 1.f);
}

// ---------------------------------------------------------------------------
// FC (h @ W_fc + b_fc) fused with mean pooling via atomics
// ---------------------------------------------------------------------------
__global__ __launch_bounds__(256) void fc_pool_kernel(const float* __restrict__ h,
                                                      const float* __restrict__ Wfc,
                                                      const float* __restrict__ bfc,
                                                      const int* __restrict__ batch,
                                                      const float* __restrict__ ginv,
                                                      float* __restrict__ out) {
    __shared__ float hs[16][128];
    __shared__ float wf[128][10];
    __shared__ float bf[10];
    int b0 = blockIdx.x * 16;
    int t = threadIdx.x;
    for (int i = t; i < 128 * 10; i += 256) wf[i / 10][i % 10] = Wfc[i];
    if (t < 10) bf[t] = bfc[t];
    for (int i = t; i < 16 * 32; i += 256) {
        int r = i >> 5, c4 = i & 31;
        int row = b0 + r;
        float4 v = make_float4(0.f, 0.f, 0.f, 0.f);
        if (row < Nn) v = *(const float4*)(h + (size_t)row * 128 + c4 * 4);
        *(float4*)(&hs[r][c4 * 4]) = v;
    }
    __syncthreads();
    if (t < 160) {
        int r = t / 10, c = t % 10;
        int row = b0 + r;
        if (row < Nn) {
            float acc = bf[c];
            #pragma unroll
            for (int k = 0; k < 128; ++k) acc = fmaf(hs[r][k], wf[k][c], acc);
            int g = batch[row];
            atomicAdd(out + g * 10 + c, acc * ginv[g]);
        }
    }
}

// ---------------------------------------------------------------------------
// Launch
// ---------------------------------------------------------------------------
extern "C" void kernel_launch(void* const* d_in, const int* in_sizes, int n_in,
                              void* d_out, int out_size, void* d_ws, size_t ws_size,
                              hipStream_t stream) {
    const float* x_seq = (const float*)d_in[0];
    const int*   eidx  = (const int*)d_in[1];
    const int*   batch = (const int*)d_in[2];
    const float* W_gcn = (const float*)d_in[3];
    const float* b_gcn = (const float*)d_in[4];
    const float* W_ih  = (const float*)d_in[5];
    const float* W_hh  = (const float*)d_in[6];
    const float* b_ih  = (const float*)d_in[7];
    const float* b_hh  = (const float*)d_in[8];
    const float* W_fc  = (const float*)d_in[9];
    const float* b_fc  = (const float*)d_in[10];
    const int* src = eidx;
    const int* dst = eidx + Ee;
    float* out = (float*)d_out;

    size_t woff = 0;
    auto alloc = [&](size_t bytes) -> void* {
        void* p = (char*)d_ws + woff;
        woff = (woff + bytes + 255) & ~(size_t)255;
        return p;
    };
    int*   counts  = (int*)alloc(Nn * 4);
    int*   cursor  = (int*)alloc(Nn * 4);
    int*   incl    = (int*)alloc(Nn * 4);
    int*   blksum  = (int*)alloc(256 * 4);
    int*   offx    = (int*)alloc(Nn * 4);
    int*   csr_src = (int*)alloc(Ee * 4);
    float* csr_w   = (float*)alloc(Ee * 4);
    float* dis     = (float*)alloc(Nn * 4);
    unsigned short* wg_hi  = (unsigned short*)alloc(128 * 128 * 2);
    unsigned short* wg_lo  = (unsigned short*)alloc(128 * 128 * 2);
    unsigned short* wih_hi = (unsigned short*)alloc(384 * 128 * 2);
    unsigned short* wih_lo = (unsigned short*)alloc(384 * 128 * 2);
    unsigned short* whh_hi = (unsigned short*)alloc(384 * 128 * 2);
    unsigned short* whh_lo = (unsigned short*)alloc(384 * 128 * 2);
    float* ginv = (float*)alloc(256);
    float* xwp   = (float*)alloc((size_t)NT * 128 * 4);   // 204.8 MB, [n][t][128]
    __half* gx16 = (__half*)alloc((size_t)NT * 384 * 2);  // 307.2 MB, [t][n][384]
    float* hbuf  = (float*)alloc((size_t)Nn * 128 * 4);   // 25.6 MB

    hipMemsetAsync(counts, 0, Nn * 4, stream);
    hipMemsetAsync(cursor, 0, Nn * 4, stream);
    hipMemsetAsync(d_out, 0, (size_t)Gg * Cc * 4, stream);

    const int nbN = (Nn + 255) / 256;
    const int nbE = (Ee + 255) / 256;

    count_deg_kernel<<<nbE, 256, 0, stream>>>(dst, counts);
    dis_kernel<<<nbN, 256, 0, stream>>>(counts, dis);
    scan_block_kernel<<<nbN, 256, 0, stream>>>(counts, incl, blksum);
    scan_tops_kernel<<<1, 256, 0, stream>>>(blksum, nbN);
    scan_fix_kernel<<<nbN, 256, 0, stream>>>(counts, incl, blksum, offx);
    fill_csr_kernel<<<nbE, 256, 0, stream>>>(src, dst, dis, offx, cursor, csr_src, csr_w);

    wsplit_kernel<<<(384 * 128 + 255) / 256, 256, 0, stream>>>(W_ih, wih_hi, wih_lo, 384 * 128);
    wsplit_kernel<<<(384 * 128 + 255) / 256, 256, 0, stream>>>(W_hh, whh_hi, whh_lo, 384 * 128);
    wgcnT_kernel<<<(128 * 128 + 255) / 256, 256, 0, stream>>>(W_gcn, wg_hi, wg_lo);
    gcount_bs_kernel<<<1, 64, 0, stream>>>(batch, ginv);

    // xw for all T, output [n][t][128]
    xw_gemm<<<NT / 128, 256, 0, stream>>>(x_seq, wg_hi, wg_lo, xwp);
    // fused aggregation + gx GEMM (gcn stays in LDS); gx out as [t][n][384]
    aggx_kernel<<<Nn / 8, 256, 0, stream>>>(xwp, dis, offx, counts, csr_src, csr_w,
                                            b_gcn, wih_hi, wih_lo, b_ih, gx16);
    // GRU v2: 1 wave / 16 nodes, no barriers, register-local gate
    gru_kernel<<<Nn / 16, 64, 0, stream>>>(whh_hi, whh_lo, gx16, b_hh, hbuf);

    fc_pool_kernel<<<(Nn + 15) / 16, 256, 0, stream>>>(hbuf, W_fc, b_fc, batch, ginv, out);
}

// Round 9
// 1672.755 us; speedup vs baseline: 1.3532x; 1.3532x over previous
//
#include <hip/hip_runtime.h>
#include <hip/hip_bf16.h>
#include <hip/hip_fp16.h>
#include <cstddef>
#include <cstdint>

// Problem constants (from reference)
#define Nn 50000
#define Ee 800000
#define Tt 8
#define Ff 128
#define Hh 128
#define Cc 10
#define Gg 64
#define NT 400000    // Tt * Nn

typedef __attribute__((ext_vector_type(8))) short bf16x8;
typedef __attribute__((ext_vector_type(4))) float f32x4;

__device__ inline unsigned short f2bf(float x) {
    __hip_bfloat16 b = __float2bfloat16(x);
    return *reinterpret_cast<unsigned short*>(&b);
}
__device__ inline float bf2f(unsigned short u) {
    __hip_bfloat16 b = *reinterpret_cast<__hip_bfloat16*>(&u);
    return __bfloat162float(b);
}
__device__ inline void split2(float x, unsigned short& h, unsigned short& l) {
    h = f2bf(x);
    l = f2bf(x - bf2f(h));
}

// ---------------------------------------------------------------------------
// Degree / normalization / CSR build
// ---------------------------------------------------------------------------
__global__ __launch_bounds__(256) void count_deg_kernel(const int* __restrict__ dst,
                                                        int* __restrict__ counts) {
    int e = blockIdx.x * 256 + threadIdx.x;
    if (e < Ee) atomicAdd(&counts[dst[e]], 1);
}

__global__ __launch_bounds__(256) void dis_kernel(const int* __restrict__ counts,
                                                  float* __restrict__ dis) {
    int i = blockIdx.x * 256 + threadIdx.x;
    if (i < Nn) dis[i] = 1.0f / sqrtf((float)counts[i] + 1.0f);
}

__global__ __launch_bounds__(256) void scan_block_kernel(const int* __restrict__ counts,
                                                         int* __restrict__ incl,
                                                         int* __restrict__ blksum) {
    __shared__ int s[256];
    int t = threadIdx.x;
    int i = blockIdx.x * 256 + t;
    int v = (i < Nn) ? counts[i] : 0;
    s[t] = v;
    __syncthreads();
    #pragma unroll
    for (int d = 1; d < 256; d <<= 1) {
        int add = (t >= d) ? s[t - d] : 0;
        __syncthreads();
        s[t] += add;
        __syncthreads();
    }
    if (i < Nn) incl[i] = s[t];
    if (t == 255) blksum[blockIdx.x] = s[255];
}

__global__ __launch_bounds__(256) void scan_tops_kernel(int* __restrict__ blksum, int nb) {
    __shared__ int s[256];
    int t = threadIdx.x;
    int v = (t < nb) ? blksum[t] : 0;
    s[t] = v;
    __syncthreads();
    #pragma unroll
    for (int d = 1; d < 256; d <<= 1) {
        int add = (t >= d) ? s[t - d] : 0;
        __syncthreads();
        s[t] += add;
        __syncthreads();
    }
    if (t < nb) blksum[t] = s[t] - v;  // exclusive
}

__global__ __launch_bounds__(256) void scan_fix_kernel(const int* __restrict__ counts,
                                                       const int* __restrict__ incl,
                                                       const int* __restrict__ blksum,
                                                       int* __restrict__ off) {
    int i = blockIdx.x * 256 + threadIdx.x;
    if (i < Nn) off[i] = incl[i] - counts[i] + blksum[i >> 8];
}

__global__ __launch_bounds__(256) void fill_csr_kernel(const int* __restrict__ src,
                                                       const int* __restrict__ dst,
                                                       const float* __restrict__ dis,
                                                       const int* __restrict__ off,
                                                       int* __restrict__ cursor,
                                                       int* __restrict__ csr_src,
                                                       float* __restrict__ csr_w) {
    int e = blockIdx.x * 256 + threadIdx.x;
    if (e >= Ee) return;
    int s = src[e], d = dst[e];
    int slot = off[d] + atomicAdd(&cursor[d], 1);
    csr_src[slot] = s;
    csr_w[slot] = dis[s] * dis[d];
}

// ---------------------------------------------------------------------------
// Weight split kernels (fp32 -> bf16 hi/lo, layout B^T [col][K])
// ---------------------------------------------------------------------------
__global__ __launch_bounds__(256) void wsplit_kernel(const float* __restrict__ W,
                                                     unsigned short* __restrict__ bh,
                                                     unsigned short* __restrict__ bl, int n) {
    int i = blockIdx.x * 256 + threadIdx.x;
    if (i >= n) return;
    unsigned short h, l;
    split2(W[i], h, l);
    bh[i] = h;
    bl[i] = l;
}

__global__ __launch_bounds__(256) void wgcnT_kernel(const float* __restrict__ W,
                                                    unsigned short* __restrict__ bh,
                                                    unsigned short* __restrict__ bl) {
    int i = blockIdx.x * 256 + threadIdx.x;
    if (i >= 128 * 128) return;
    int f = i >> 7, hc = i & 127;
    unsigned short h, l;
    split2(W[i], h, l);
    bh[hc * 128 + f] = h;
    bl[hc * 128 + f] = l;
}

// ---------------------------------------------------------------------------
// xw GEMM: xwp[(n*8+t)][128] = x_seq[(t*Nn+n)][128] @ W_gcn, split-bf16 MFMA.
// ---------------------------------------------------------------------------
__global__ __launch_bounds__(256) void xw_gemm(const float* __restrict__ X,
                                               const unsigned short* __restrict__ BTh,
                                               const unsigned short* __restrict__ BTl,
                                               float* __restrict__ Cout) {
    __shared__ __align__(16) char lds[32768];
    char* pAh = lds;
    char* pAl = lds + 16384;
    const int bm = blockIdx.x * 128;
    const int tid = threadIdx.x;
    const int wid = tid >> 6, lane = tid & 63;
    const int wr = wid >> 1, wc = wid & 1;
    const int l15 = lane & 15, l4 = lane >> 4;

    f32x4 acc[4][4] = {};

    for (int kh = 0; kh < 2; ++kh) {
        if (kh) __syncthreads();
        #pragma unroll
        for (int i = 0; i < 8; ++i) {
            int idx = tid + i * 256;
            int row = idx >> 4;
            int k4 = idx & 15;
            float4 v = *(const float4*)(X + (size_t)(bm + row) * 128 + kh * 64 + k4 * 4);
            ushort4 h, l;
            split2(v.x, h.x, l.x);
            split2(v.y, h.y, l.y);
            split2(v.z, h.z, l.z);
            split2(v.w, h.w, l.w);
            int off = row * 128 + ((k4 * 8) ^ ((row & 7) << 4));
            *(ushort4*)(pAh + off) = h;
            *(ushort4*)(pAl + off) = l;
        }
        __syncthreads();

        #pragma unroll
        for (int kq = 0; kq < 2; ++kq) {
            bf16x8 a_h[4], a_l[4], b_h[4], b_l[4];
            const int kbase = kq * 64 + l4 * 16;
            #pragma unroll
            for (int m = 0; m < 4; ++m) {
                const int r = wr * 64 + m * 16 + l15;
                const int byteo = r * 128 + (kbase ^ ((r & 7) << 4));
                a_h[m] = *(const bf16x8*)(pAh + byteo);
                a_l[m] = *(const bf16x8*)(pAl + byteo);
            }
            #pragma unroll
            for (int n = 0; n < 4; ++n) {
                const int col = wc * 64 + n * 16 + l15;
                const size_t bo = (size_t)col * 128 + kh * 64 + kq * 32 + l4 * 8;
                b_h[n] = *(const bf16x8*)(BTh + bo);
                b_l[n] = *(const bf16x8*)(BTl + bo);
            }
            #pragma unroll
            for (int m = 0; m < 4; ++m)
                #pragma unroll
                for (int n = 0; n < 4; ++n) {
                    acc[m][n] = __builtin_amdgcn_mfma_f32_16x16x32_bf16(a_h[m], b_h[n],
                                                                        acc[m][n], 0, 0, 0);
                    acc[m][n] = __builtin_amdgcn_mfma_f32_16x16x32_bf16(a_h[m], b_l[n],
                                                                        acc[m][n], 0, 0, 0);
                    acc[m][n] = __builtin_amdgcn_mfma_f32_16x16x32_bf16(a_l[m], b_h[n],
                                                                        acc[m][n], 0, 0, 0);
                }
        }
    }

    // epilogue: remap GEMM row r = t*Nn + n  ->  output row n*8 + t
    #pragma unroll
    for (int m = 0; m < 4; ++m) {
        const int row = bm + wr * 64 + m * 16 + l4 * 4;
        #pragma unroll
        for (int q = 0; q < 4; ++q) {
            const int r = row + q;
            const int tt = r / Nn;
            const int nn = r - tt * Nn;
            float* outrow = Cout + ((size_t)nn * 8 + tt) * 128;
            #pragma unroll
            for (int n = 0; n < 4; ++n) {
                const int col = wc * 64 + n * 16 + l15;
                outrow[col] = acc[m][n][q];
            }
        }
    }
}

// ---------------------------------------------------------------------------
// FUSED aggregation + gx GEMM. One block = 8 nodes = 64 rows.
// Phase A: gather xwp 4KB node-blocks (gcn stays in LDS, bf16 hi/lo swizzled).
// Phase B: gx = gcn @ W_ih^T + b_ih -> fp16, layout [t][n][384] with intra-row
//          bytes XOR-swizzled by (node&7)<<4 so the GRU's global_load_lds
//          (linear dest) + swizzled LDS reads are bank-conflict-reduced.
// ---------------------------------------------------------------------------
__global__ __launch_bounds__(256) void aggx_kernel(const float* __restrict__ xwp,
                                                   const float* __restrict__ dis,
                                                   const int* __restrict__ off,
                                                   const int* __restrict__ counts,
                                                   const int* __restrict__ csr_src,
                                                   const float* __restrict__ csr_w,
                                                   const float* __restrict__ b_gcn,
                                                   const unsigned short* __restrict__ BTh,
                                                   const unsigned short* __restrict__ BTl,
                                                   const float* __restrict__ bias,
                                                   __half* __restrict__ gx16) {
    __shared__ __align__(16) char lds[32768];  // gcn hi 16KB + lo 16KB
    char* pAh = lds;
    char* pAl = lds + 16384;
    const int n0 = blockIdx.x * 8;
    const int tid = threadIdx.x;
    const int wid = tid >> 6, lane = tid & 63;
    const int l15 = lane & 15, l4 = lane >> 4;

    // ---- Phase A: aggregate 2 nodes per wave ----
    for (int nl = 0; nl < 2; ++nl) {
        const int n = n0 + wid * 2 + nl;
        const float dv = dis[n];
        const float dsq = dv * dv;
        const float* bn_ = xwp + (size_t)n * 1024 + lane * 4;
        f32x4 acc[4];
        #pragma unroll
        for (int p = 0; p < 4; ++p) acc[p] = (*(const f32x4*)(bn_ + p * 256)) * dsq;

        const int s0 = off[n];
        const int cnt = counts[n];
        for (int base = 0; base < cnt; base += 64) {
            const int m = min(64, cnt - base);
            int idxv = 0;
            float wvv = 0.f;
            {
                int j = base + lane;
                if (j < cnt) {
                    idxv = csr_src[s0 + j];
                    wvv = csr_w[s0 + j];
                }
            }
            int sA = __shfl(idxv, 0);
            float wA = __shfl(wvv, 0);
            const float* pA = xwp + (size_t)sA * 1024 + lane * 4;
            f32x4 v0 = *(const f32x4*)(pA);
            f32x4 v1 = *(const f32x4*)(pA + 256);
            f32x4 v2 = *(const f32x4*)(pA + 512);
            f32x4 v3 = *(const f32x4*)(pA + 768);
            for (int k = 0; k < m; ++k) {
                f32x4 u0 = v0, u1 = v1, u2 = v2, u3 = v3;
                const float w = wA;
                if (k + 1 < m) {
                    sA = __shfl(idxv, k + 1);
                    wA = __shfl(wvv, k + 1);
                    const float* pN = xwp + (size_t)sA * 1024 + lane * 4;
                    v0 = *(const f32x4*)(pN);
                    v1 = *(const f32x4*)(pN + 256);
                    v2 = *(const f32x4*)(pN + 512);
                    v3 = *(const f32x4*)(pN + 768);
                }
                acc[0] += u0 * w;
                acc[1] += u1 * w;
                acc[2] += u2 * w;
                acc[3] += u3 * w;
            }
        }

        #pragma unroll
        for (int p = 0; p < 4; ++p) {
            const int q = p * 1024 + lane * 16;  // byte in node's 4KB block
            const int t = q >> 9;
            const int c0 = (q & 511) >> 2;
            float4 bb = *(const float4*)(b_gcn + c0);
            float w0 = fmaxf(acc[p][0] + bb.x, 0.f);
            float w1 = fmaxf(acc[p][1] + bb.y, 0.f);
            float w2 = fmaxf(acc[p][2] + bb.z, 0.f);
            float w3 = fmaxf(acc[p][3] + bb.w, 0.f);
            ushort4 oh, ol;
            split2(w0, oh.x, ol.x);
            split2(w1, oh.y, ol.y);
            split2(w2, oh.z, ol.z);
            split2(w3, oh.w, ol.w);
            const int r = (wid * 2 + nl) * 8 + t;        // local row, r&7 == t
            const int byteo = r * 256 + ((c0 * 2) ^ (t << 4));
            *(ushort4*)(pAh + byteo) = oh;
            *(ushort4*)(pAl + byteo) = ol;
        }
    }
    __syncthreads();

    // ---- Phase B: gx = gcn @ W_ih^T + b_ih, wave owns 96 cols ----
    f32x4 acc[4][6] = {};
    const int wc0 = wid * 96;
    #pragma unroll
    for (int kq = 0; kq < 4; ++kq) {
        bf16x8 a_h[4], a_l[4];
        const int kbase = kq * 64 + l4 * 16;
        #pragma unroll
        for (int m = 0; m < 4; ++m) {
            const int r = m * 16 + l15;
            const int byteo = r * 256 + (kbase ^ ((r & 7) << 4));
            a_h[m] = *(const bf16x8*)(pAh + byteo);
            a_l[m] = *(const bf16x8*)(pAl + byteo);
        }
        #pragma unroll
        for (int n = 0; n < 6; ++n) {
            const int col = wc0 + n * 16 + l15;
            const size_t bo = (size_t)col * 128 + kq * 32 + l4 * 8;
            bf16x8 b_h = *(const bf16x8*)(BTh + bo);
            bf16x8 b_l = *(const bf16x8*)(BTl + bo);
            #pragma unroll
            for (int m = 0; m < 4; ++m) {
                acc[m][n] = __builtin_amdgcn_mfma_f32_16x16x32_bf16(a_h[m], b_h,
                                                                    acc[m][n], 0, 0, 0);
                acc[m][n] = __builtin_amdgcn_mfma_f32_16x16x32_bf16(a_h[m], b_l,
                                                                    acc[m][n], 0, 0, 0);
                acc[m][n] = __builtin_amdgcn_mfma_f32_16x16x32_bf16(a_l[m], b_h,
                                                                    acc[m][n], 0, 0, 0);
            }
        }
    }

    // epilogue: local row lr = node_local*8 + t  ->  gx row t*Nn + node,
    // intra-row byte XOR-swizzled by (node&7)<<4
    #pragma unroll
    for (int n = 0; n < 6; ++n) {
        const int col = wc0 + n * 16 + l15;
        const float bb = bias[col];
        #pragma unroll
        for (int m = 0; m < 4; ++m) {
            #pragma unroll
            for (int q = 0; q < 4; ++q) {
                const int lr = m * 16 + l4 * 4 + q;
                const int tt = lr & 7;
                const int node = n0 + (lr >> 3);
                const size_t rowb = ((size_t)tt * Nn + node) * 768;
                const int cb = (col * 2) ^ ((node & 7) << 4);
                *(__half*)((char*)gx16 + rowb + cb) = __float2half(acc[m][n][q] + bb);
            }
        }
    }
}

// ---------------------------------------------------------------------------
// GRU v3: single launch, block = 64 nodes, 4 waves. Wave w owns col tiles
// {32w+16tt + 128g : tt in {0,1}, g in {0,1,2}} -> gate is register-local
// (lane holds gh at c, c+128, c+256 AND the h it updates), while A (h) and
// B (W_hh) keep block-level reuse. Per step: bar; h->LDS (bf16 hi/lo,
// XOR-swizzled); bar; issue 48KB gx DMA; 72 MFMA (A LDS-shared, B from L2,
// read once per block); bar (drains vmcnt -> DMA landed); gate from LDS.
// h lives in registers across all 8 steps; never touches global until the end.
// ---------------------------------------------------------------------------
__global__ __launch_bounds__(256, 2) void gru_kernel(const unsigned short* __restrict__ BTh,
                                                     const unsigned short* __restrict__ BTl,
                                                     const __half* __restrict__ gx,
                                                     const float* __restrict__ b_hh,
                                                     float* __restrict__ hbuf) {
    __shared__ __align__(16) char lds[81920];  // hHi 16K | hLo 16K | gxS 48K
    char* pHh = lds;
    char* pHl = lds + 16384;
    char* gxS = lds + 32768;
    const int tid = threadIdx.x;
    const int wid = tid >> 6, lane = tid & 63;
    const int l15 = lane & 15, l4 = lane >> 4;
    const int n0 = blockIdx.x * 64;

    // biases for this lane's 2 cols per gate group
    float bh[3][2];
    #pragma unroll
    for (int g = 0; g < 3; ++g)
        #pragma unroll
        for (int tt = 0; tt < 2; ++tt)
            bh[g][tt] = b_hh[g * 128 + wid * 32 + tt * 16 + l15];

    #define ISSUE_GX(T)                                                                  \
        {                                                                                \
            const char* srcb = (const char*)(gx + ((size_t)(T) * Nn + n0) * 384);        \
            _Pragma("unroll")                                                            \
            for (int i = 0; i < 12; ++i) {                                               \
                const int o = i * 4096 + tid * 16;                                       \
                __builtin_amdgcn_global_load_lds(                                        \
                    (const __attribute__((address_space(1))) void*)(srcb + o),           \
                    (__attribute__((address_space(3))) void*)(gxS + o), 16, 0, 0);       \
            }                                                                            \
        }

    float h[32];  // h[m*8 + q*2 + tt] = h[node=m*16+l4*4+q][col=wid*32+tt*16+l15]

    // ---- t = 0: gh = 0 (h=0) ----
    ISSUE_GX(0);
    __syncthreads();  // drains vmcnt -> gx tile landed (all waves)
    #pragma unroll
    for (int m = 0; m < 4; ++m) {
        #pragma unroll
        for (int q = 0; q < 4; ++q) {
            const int nl = m * 16 + l4 * 4 + q;
            const char* rp = gxS + nl * 768;
            const int key = (nl & 7) << 4;
            #pragma unroll
            for (int tt = 0; tt < 2; ++tt) {
                const int c0 = wid * 32 + tt * 16 + l15;
                float xr = __half2float(*(const __half*)(rp + ((2 * c0) ^ key)));
                float xz = __half2float(*(const __half*)(rp + ((2 * (c0 + 128)) ^ key)));
                float xn = __half2float(*(const __half*)(rp + ((2 * (c0 + 256)) ^ key)));
                float rg = 1.f / (1.f + expf(-(xr + bh[0][tt])));
                float zg = 1.f / (1.f + expf(-(xz + bh[1][tt])));
                float ng = tanhf(xn + rg * bh[2][tt]);
                h[m * 8 + q * 2 + tt] = (1.f - zg) * ng;
            }
        }
    }

    for (int t = 1; t < Tt; ++t) {
        __syncthreads();  // bar1: all waves' gates (and MFMA A-reads) of t-1 done
        // ---- h -> LDS (bf16 hi/lo, XOR-swizzled) ----
        #pragma unroll
        for (int m = 0; m < 4; ++m) {
            #pragma unroll
            for (int q = 0; q < 4; ++q) {
                const int nl = m * 16 + l4 * 4 + q;
                const int key = (nl & 7) << 4;
                #pragma unroll
                for (int tt = 0; tt < 2; ++tt) {
                    const int c0 = wid * 32 + tt * 16 + l15;
                    unsigned short sh, sl;
                    split2(h[m * 8 + q * 2 + tt], sh, sl);
                    const int byteo = nl * 256 + ((2 * c0) ^ key);
                    *(unsigned short*)(pHh + byteo) = sh;
                    *(unsigned short*)(pHl + byteo) = sl;
                }
            }
        }
        __syncthreads();  // bar2: h tile complete
        ISSUE_GX(t);      // async: lands during the MFMA phase

        // ---- MFMA: gh = h @ W_hh^T, 64 rows x 192 cols per wave ----
        f32x4 acc[4][6];
        #pragma unroll
        for (int m = 0; m < 4; ++m)
            #pragma unroll
            for (int j = 0; j < 6; ++j) acc[m][j] = (f32x4){0.f, 0.f, 0.f, 0.f};
        const int akey = (l15 & 7) << 4;
        #pragma unroll
        for (int kq = 0; kq < 4; ++kq) {
            bf16x8 a_h[4], a_l[4];
            #pragma unroll
            for (int m = 0; m < 4; ++m) {
                const int ab = (m * 16 + l15) * 256 + ((kq * 64 + l4 * 16) ^ akey);
                a_h[m] = *(const bf16x8*)(pHh + ab);
                a_l[m] = *(const bf16x8*)(pHl + ab);
            }
            #pragma unroll
            for (int j = 0; j < 6; ++j) {
                const int g = j >> 1, tt = j & 1;
                const int col = g * 128 + wid * 32 + tt * 16 + l15;
                const size_t bo = (size_t)col * 128 + kq * 32 + l4 * 8;
                bf16x8 b_h = *(const bf16x8*)(BTh + bo);
                bf16x8 b_l = *(const bf16x8*)(BTl + bo);
                #pragma unroll
                for (int m = 0; m < 4; ++m) {
                    acc[m][j] = __builtin_amdgcn_mfma_f32_16x16x32_bf16(a_h[m], b_h,
                                                                       acc[m][j], 0, 0, 0);
                    acc[m][j] = __builtin_amdgcn_mfma_f32_16x16x32_bf16(a_h[m], b_l,
                                                                       acc[m][j], 0, 0, 0);
                    acc[m][j] = __builtin_amdgcn_mfma_f32_16x16x32_bf16(a_l[m], b_h,
                                                                       acc[m][j], 0, 0, 0);
                }
            }
        }
        __syncthreads();  // bar3: per-wave vmcnt(0) drain + barrier -> gx landed

        // ---- gate (register-local) ----
        #pragma unroll
        for (int m = 0; m < 4; ++m) {
            #pragma unroll
            for (int q = 0; q < 4; ++q) {
                const int nl = m * 16 + l4 * 4 + q;
                const char* rp = gxS + nl * 768;
                const int key = (nl & 7) << 4;
                #pragma unroll
                for (int tt = 0; tt < 2; ++tt) {
                    const int c0 = wid * 32 + tt * 16 + l15;
                    float xr = __half2float(*(const __half*)(rp + ((2 * c0) ^ key)));
                    float xz = __half2float(*(const __half*)(rp + ((2 * (c0 + 128)) ^ key)));
                    float xn = __half2float(*(const __half*)(rp + ((2 * (c0 + 256)) ^ key)));
                    float ghr = acc[m][0 + tt][q] + bh[0][tt];
                    float ghz = acc[m][2 + tt][q] + bh[1][tt];
                    float ghn = acc[m][4 + tt][q] + bh[2][tt];
                    float rg = 1.f / (1.f + expf(-(xr + ghr)));
                    float zg = 1.f / (1.f + expf(-(xz + ghz)));
                    float ng = tanhf(xn + rg * ghn);
                    const int hi = m * 8 + q * 2 + tt;
                    h[hi] = (1.f - zg) * ng + zg * h[hi];
                }
            }
        }
    }

    // ---- write final h (fp32) ----
    #pragma unroll
    for (int m = 0; m < 4; ++m) {
        #pragma unroll
        for (int q = 0; q < 4; ++q) {
            const int row = n0 + m * 16 + l4 * 4 + q;
            if (row < Nn) {
                #pragma unroll
                for (int tt = 0; tt < 2; ++tt)
                    hbuf[(size_t)row * 128 + wid * 32 + tt * 16 + l15] =
                        h[m * 8 + q * 2 + tt];
            }
        }
    }
    #undef ISSUE_GX
}

// ---------------------------------------------------------------------------
// Graph sizes by binary search on the SORTED batch array
// ---------------------------------------------------------------------------
__global__ void gcount_bs_kernel(const int* __restrict__ batch, float* __restrict__ ginv) {
    int g = threadIdx.x;
    if (g >= Gg) return;
    int lo = 0, hi = Nn;
    while (lo < hi) {
        int m = (lo + hi) >> 1;
        if (batch[m] < g) lo = m + 1; else hi = m;
    }
    int start = lo;
    lo = 0; hi = Nn;
    while (lo < hi) {
        int m = (lo + hi) >> 1;
        if (batch[m] <= g) lo = m + 1; else hi = m;
    }
    ginv[g] = 1.f / fmaxf((float)(lo - start), 1.f);
}

// ---------------------------------------------------------------------------
// FC (h @ W_fc + b_fc) fused with mean pooling via atomics
// ---------------------------------------------------------------------------
__global__ __launch_bounds__(256) void fc_pool_kernel(const float* __restrict__ h,
                                                      const float* __restrict__ Wfc,
                                                      const float* __restrict__ bfc,
                                                      const int* __restrict__ batch,
                                                      const float* __restrict__ ginv,
                                                      float* __restrict__ out) {
    __shared__ float hs[16][128];
    __shared__ float wf[128][10];
    __shared__ float bf[10];
    int b0 = blockIdx.x * 16;
    int t = threadIdx.x;
    for (int i = t; i < 128 * 10; i += 256) wf[i / 10][i % 10] = Wfc[i];
    if (t < 10) bf[t] = bfc[t];
    for (int i = t; i < 16 * 32; i += 256) {
        int r = i >> 5, c4 = i & 31;
        int row = b0 + r;
        float4 v = make_float4(0.f, 0.f, 0.f, 0.f);
        if (row < Nn) v = *(const float4*)(h + (size_t)row * 128 + c4 * 4);
        *(float4*)(&hs[r][c4 * 4]) = v;
    }
    __syncthreads();
    if (t < 160) {
        int r = t / 10, c = t % 10;
        int row = b0 + r;
        if (row < Nn) {
            float acc = bf[c];
            #pragma unroll
            for (int k = 0; k < 128; ++k) acc = fmaf(hs[r][k], wf[k][c], acc);
            int g = batch[row];
            atomicAdd(out + g * 10 + c, acc * ginv[g]);
        }
    }
}

// ---------------------------------------------------------------------------
// Launch
// ---------------------------------------------------------------------------
extern "C" void kernel_launch(void* const* d_in, const int* in_sizes, int n_in,
                              void* d_out, int out_size, void* d_ws, size_t ws_size,
                              hipStream_t stream) {
    const float* x_seq = (const float*)d_in[0];
    const int*   eidx  = (const int*)d_in[1];
    const int*   batch = (const int*)d_in[2];
    const float* W_gcn = (const float*)d_in[3];
    const float* b_gcn = (const float*)d_in[4];
    const float* W_ih  = (const float*)d_in[5];
    const float* W_hh  = (const float*)d_in[6];
    const float* b_ih  = (const float*)d_in[7];
    const float* b_hh  = (const float*)d_in[8];
    const float* W_fc  = (const float*)d_in[9];
    const float* b_fc  = (const float*)d_in[10];
    const int* src = eidx;
    const int* dst = eidx + Ee;
    float* out = (float*)d_out;

    size_t woff = 0;
    auto alloc = [&](size_t bytes) -> void* {
        void* p = (char*)d_ws + woff;
        woff = (woff + bytes + 255) & ~(size_t)255;
        return p;
    };
    int*   counts  = (int*)alloc(Nn * 4);
    int*   cursor  = (int*)alloc(Nn * 4);
    int*   incl    = (int*)alloc(Nn * 4);
    int*   blksum  = (int*)alloc(256 * 4);
    int*   offx    = (int*)alloc(Nn * 4);
    int*   csr_src = (int*)alloc(Ee * 4);
    float* csr_w   = (float*)alloc(Ee * 4);
    float* dis     = (float*)alloc(Nn * 4);
    unsigned short* wg_hi  = (unsigned short*)alloc(128 * 128 * 2);
    unsigned short* wg_lo  = (unsigned short*)alloc(128 * 128 * 2);
    unsigned short* wih_hi = (unsigned short*)alloc(384 * 128 * 2);
    unsigned short* wih_lo = (unsigned short*)alloc(384 * 128 * 2);
    unsigned short* whh_hi = (unsigned short*)alloc(384 * 128 * 2);
    unsigned short* whh_lo = (unsigned short*)alloc(384 * 128 * 2);
    float* ginv = (float*)alloc(256);
    float* xwp   = (float*)alloc((size_t)NT * 128 * 4);   // 204.8 MB, [n][t][128]
    __half* gx16 = (__half*)alloc((size_t)NT * 384 * 2);  // 307.2 MB, [t][n][384] swz
    float* hbuf  = (float*)alloc((size_t)Nn * 128 * 4);   // 25.6 MB (also DMA tail pad)

    hipMemsetAsync(counts, 0, Nn * 4, stream);
    hipMemsetAsync(cursor, 0, Nn * 4, stream);
    hipMemsetAsync(d_out, 0, (size_t)Gg * Cc * 4, stream);

    const int nbN = (Nn + 255) / 256;
    const int nbE = (Ee + 255) / 256;

    count_deg_kernel<<<nbE, 256, 0, stream>>>(dst, counts);
    dis_kernel<<<nbN, 256, 0, stream>>>(counts, dis);
    scan_block_kernel<<<nbN, 256, 0, stream>>>(counts, incl, blksum);
    scan_tops_kernel<<<1, 256, 0, stream>>>(blksum, nbN);
    scan_fix_kernel<<<nbN, 256, 0, stream>>>(counts, incl, blksum, offx);
    fill_csr_kernel<<<nbE, 256, 0, stream>>>(src, dst, dis, offx, cursor, csr_src, csr_w);

    wsplit_kernel<<<(384 * 128 + 255) / 256, 256, 0, stream>>>(W_ih, wih_hi, wih_lo, 384 * 128);
    wsplit_kernel<<<(384 * 128 + 255) / 256, 256, 0, stream>>>(W_hh, whh_hi, whh_lo, 384 * 128);
    wgcnT_kernel<<<(128 * 128 + 255) / 256, 256, 0, stream>>>(W_gcn, wg_hi, wg_lo);
    gcount_bs_kernel<<<1, 64, 0, stream>>>(batch, ginv);

    // xw for all T, output [n][t][128]
    xw_gemm<<<NT / 128, 256, 0, stream>>>(x_seq, wg_hi, wg_lo, xwp);
    // fused aggregation + gx GEMM (gcn stays in LDS); gx out [t][n][384] swizzled
    aggx_kernel<<<Nn / 8, 256, 0, stream>>>(xwp, dis, offx, counts, csr_src, csr_w,
                                            b_gcn, wih_hi, wih_lo, b_ih, gx16);
    // GRU v3: block-level B reuse + register-local gate, h in regs all 8 steps
    gru_kernel<<<(Nn + 63) / 64, 256, 0, stream>>>(whh_hi, whh_lo, gx16, b_hh, hbuf);

    fc_pool_kernel<<<(Nn + 15) / 16, 256, 0, stream>>>(hbuf, W_fc, b_fc, batch, ginv, out);
}